// Round 1
// baseline (10.154 us; speedup 1.0000x reference)
//
#include <hip/hip_runtime.h>

// Closed-form of the reference:
//   x <- min(max(x + c - t, 0), 1) iterated 1000x, c = 0.01*adj*(adj>0.5), t = 2e-5
//   adj <= 0.5 : c=0, x decays to <= 0.5, final threshold -> 0
//   adj >  0.5 : c-t > 0.00498, x saturates to exactly 1.0 within ~100 iters -> 1.0
// => out[i] = adj[i] > 0.5f ? 1.0f : 0.0f   (bit-exact vs fp32 reference)

__global__ __launch_bounds__(256) void spp_threshold_kernel(
    const float4* __restrict__ in, float4* __restrict__ out, int n4) {
    int i = blockIdx.x * blockDim.x + threadIdx.x;
    if (i < n4) {
        float4 v = in[i];
        float4 r;
        r.x = v.x > 0.5f ? 1.0f : 0.0f;
        r.y = v.y > 0.5f ? 1.0f : 0.0f;
        r.z = v.z > 0.5f ? 1.0f : 0.0f;
        r.w = v.w > 0.5f ? 1.0f : 0.0f;
        out[i] = r;
    }
}

extern "C" void kernel_launch(void* const* d_in, const int* in_sizes, int n_in,
                              void* d_out, int out_size, void* d_ws, size_t ws_size,
                              hipStream_t stream) {
    const float* adj = (const float*)d_in[0];
    float* out = (float*)d_out;
    int n = in_sizes[0];          // 2*1024*1024 = 2097152, divisible by 4
    int n4 = n >> 2;              // 524288
    int block = 256;
    int grid = (n4 + block - 1) / block;  // 2048 blocks
    spp_threshold_kernel<<<grid, block, 0, stream>>>(
        (const float4*)adj, (float4*)out, n4);
}

// Round 2
// 10.134 us; speedup vs baseline: 1.0019x; 1.0019x over previous
//
#include <hip/hip_runtime.h>

// Closed-form of the reference (verified bit-exact, R1 absmax=0):
//   out[i] = adj[i] > 0.5f ? 1.0f : 0.0f
//
// R2: reduce dispatch/ramp overhead — 256 blocks x 1024 threads, 32 B/thread
// (2x float4 per thread, coalesced split-load), vs R1's 2048 blocks x 16 B/thread.

__global__ __launch_bounds__(1024) void spp_threshold_kernel(
    const float4* __restrict__ in, float4* __restrict__ out, int n4) {
    int base = blockIdx.x * (blockDim.x * 2) + threadIdx.x;
    int i0 = base;
    int i1 = base + blockDim.x;

    if (i0 < n4) {
        float4 v = in[i0];
        float4 r;
        r.x = v.x > 0.5f ? 1.0f : 0.0f;
        r.y = v.y > 0.5f ? 1.0f : 0.0f;
        r.z = v.z > 0.5f ? 1.0f : 0.0f;
        r.w = v.w > 0.5f ? 1.0f : 0.0f;
        out[i0] = r;
    }
    if (i1 < n4) {
        float4 v = in[i1];
        float4 r;
        r.x = v.x > 0.5f ? 1.0f : 0.0f;
        r.y = v.y > 0.5f ? 1.0f : 0.0f;
        r.z = v.z > 0.5f ? 1.0f : 0.0f;
        r.w = v.w > 0.5f ? 1.0f : 0.0f;
        out[i1] = r;
    }
}

extern "C" void kernel_launch(void* const* d_in, const int* in_sizes, int n_in,
                              void* d_out, int out_size, void* d_ws, size_t ws_size,
                              hipStream_t stream) {
    const float* adj = (const float*)d_in[0];
    float* out = (float*)d_out;
    int n = in_sizes[0];          // 2*1024*1024 = 2097152
    int n4 = n >> 2;              // 524288 float4s
    int block = 1024;
    int per_block = block * 2;    // 2048 float4s per block
    int grid = (n4 + per_block - 1) / per_block;  // 256 blocks
    spp_threshold_kernel<<<grid, block, 0, stream>>>(
        (const float4*)adj, (float4*)out, n4);
}